// Round 4
// baseline (68.835 us; speedup 1.0000x reference)
//
#include <hip/hip_runtime.h>

#define S_      4096
#define HD      64
#define NROT    32
#define NCHUNK  32768                 // 16-vector chunks (one per (b,s) row)
#define NBLK    2048
#define WPB     4                     // waves per block
#define NWAVE   (NBLK * WPB)          // 8192
#define NITER   (NCHUNK / NWAVE)      // 4 chunks per wave

typedef __bf16 bf16x8 __attribute__((ext_vector_type(8)));
typedef float  f32x4  __attribute__((ext_vector_type(4)));
typedef unsigned short ushort_t;

// LDS address swizzle (involution, 16B-granular): spreads the transposed
// fragment reads AND the linear writes to 4 lanes per 4-bank group (the
// ds_*_b128 floor) -> conflict-free both ways.
__device__ __forceinline__ int swz(int a) { return a ^ (((a >> 8) & 7) << 4); }

// ---------------------------------------------------------------------------
// Setup: M = R(Givens scan) @ rotation_matrix, bf16, MFMA-B-fragment order
// with baked column permutation pi so the epilogue's stores coalesce:
//   fragment (kt,nt): lane l, elem i  <-  M[d][e]
//     d = kt*32 + 8*(l>>4) + i                  (K dim)
//     n = l&15;  e = 8*(n>>1) + 2*nt + (n&1)    (permuted N dim)
// ---------------------------------------------------------------------------
__global__ __launch_bounds__(256) void build_M_kernel(
    const float* __restrict__ thetas,
    const float* __restrict__ rot_pairs,
    const float* __restrict__ theta_scale,
    const float* __restrict__ rot_matrix,
    ushort_t* __restrict__ Mfrag)            // 4096 ushorts (8 KB)
{
    __shared__ float R[HD][HD + 1];
    __shared__ float RM[HD][HD];
    __shared__ float Msh[HD][HD];
    const int t = threadIdx.x;

    for (int k = t; k < HD * HD; k += 256) {
        int r = k >> 6, c = k & 63;
        R[r][c]  = (r == c) ? 1.0f : 0.0f;
        RM[r][c] = rot_matrix[k];
    }
    __syncthreads();

    if (t < HD) {
        const float ts = theta_scale[0];
        #pragma unroll 1
        for (int k = 0; k < NROT; ++k) {
            const int   i  = (int)rot_pairs[2 * k];
            const int   j  = (int)rot_pairs[2 * k + 1];
            const float th = thetas[k] * ts;
            const float sn = sinf(th);
            const float cs = cosf(th);
            const float ri = R[t][i];
            const float rj = R[t][j];
            if (i == j) {
                R[t][i] = ri * cs;   // reference's .at chain leaves G[i,i]=c
            } else {
                R[t][i] = fmaf(ri, cs,  rj * sn);
                R[t][j] = fmaf(rj, cs, -ri * sn);
            }
        }
    }
    __syncthreads();

    {
        const int e  = t & 63;
        const int dg = t >> 6;
        for (int d = dg * 16; d < dg * 16 + 16; ++d) {
            float acc = 0.0f;
            #pragma unroll
            for (int k = 0; k < HD; ++k) acc = fmaf(R[d][k], RM[k][e], acc);
            Msh[d][e] = acc;
        }
    }
    __syncthreads();

    for (int k = t; k < 8 * 512; k += 256) {
        const int f  = k >> 9;          // fragment 0..7
        const int ln = (k >> 3) & 63;   // lane
        const int i  = k & 7;           // element
        const int kt = f >> 2, nt = f & 3;
        const int d  = kt * 32 + ((ln >> 4) * 8) + i;
        const int n  = ln & 15;
        const int e  = 8 * (n >> 1) + 2 * nt + (n & 1);   // pi permutation
        union { __bf16 h; ushort_t u; } cvt;
        cvt.h = (__bf16)Msh[d][e];
        Mfrag[k] = cvt.u;
    }
}

// ---------------------------------------------------------------------------
// Main: one wave per 16-vector chunk iteration. Reg-staged:
//   global_load_dwordx4 x4 (coalesced) -> ds_write_b128 x4 (swizzled)
//   -> ds_read_b128 x4 (swizzled transpose, conflict-free) -> 8 MFMAs
//   -> RoPE epilogue (DPP shfl_xor(1)) -> 4 coalesced dwordx4 stores.
// Per-wave private LDS buffer; DS ops are in-order per wave -> no barriers.
// Next chunk's global loads issue right after ds_write frees the registers,
// so they overlap compute+stores. All waitcnts left to the compiler
// (hazard-precise).
// ---------------------------------------------------------------------------
__global__ __launch_bounds__(256, 4) void rope_mfma_kernel(
    const float* __restrict__ x,
    const ushort_t* __restrict__ Mfrag,
    const float* __restrict__ inv_freq,
    float* __restrict__ out)
{
    __shared__ __align__(16) float lbuf[WPB * 1024];   // 16 KB: 4 KB per wave
    const int t    = threadIdx.x;
    const int lane = t & 63;
    const int w    = t >> 6;
    const int l15  = lane & 15;
    const int lhi  = lane >> 4;
    const int u    = l15 >> 1;
    const bool even = (lane & 1) == 0;
    char* wbuf = reinterpret_cast<char*>(lbuf) + w * 4096;

    // B fragments (32 VGPRs)
    bf16x8 bf[2][4];
    #pragma unroll
    for (int kt = 0; kt < 2; ++kt)
        #pragma unroll
        for (int nt = 0; nt < 4; ++nt)
            bf[kt][nt] = *reinterpret_cast<const bf16x8*>(
                Mfrag + ((kt * 4 + nt) * 512 + lane * 8));

    // 4 contiguous freqs per lane: out cols 4u..4u+3 (mod 32)
    const f32x4 invf = *reinterpret_cast<const f32x4*>(inv_freq + 4 * u);
    const float INV2PI = 0.15915494309189535f;

    // precomputed swizzled LDS byte offsets
    int wr_off[4], rd_off[4];
    #pragma unroll
    for (int k = 0; k < 4; ++k) {
        wr_off[k] = swz(k * 1024 + lane * 16);
        rd_off[k] = swz(l15 * 256 + lhi * 32 + (k & 1) * 16 + (k >> 1) * 128);
    }

    int c = blockIdx.x * WPB + w;                 // first chunk for this wave

    // prologue: load chunk 0 into registers (coalesced: lane*16 B per quarter)
    f32x4 q[4];
    {
        const float* xp = x + (size_t)c * 1024 + lane * 4;
        #pragma unroll
        for (int k = 0; k < 4; ++k)
            q[k] = *reinterpret_cast<const f32x4*>(xp + k * 256);
    }

    #pragma unroll 1
    for (int it = 0; it < NITER; ++it) {
        // stage current chunk to LDS (swizzled)
        #pragma unroll
        for (int k = 0; k < 4; ++k)
            *reinterpret_cast<f32x4*>(wbuf + wr_off[k]) = q[k];

        // transposed fragment reads (conflict-free)
        f32x4 r0 = *reinterpret_cast<const f32x4*>(wbuf + rd_off[0]);
        f32x4 r1 = *reinterpret_cast<const f32x4*>(wbuf + rd_off[1]);
        f32x4 r2 = *reinterpret_cast<const f32x4*>(wbuf + rd_off[2]);
        f32x4 r3 = *reinterpret_cast<const f32x4*>(wbuf + rd_off[3]);

        // issue next chunk's loads (fly under compute + stores)
        if (it + 1 < NITER) {
            const float* xn = x + (size_t)(c + NWAVE) * 1024 + lane * 4;
            #pragma unroll
            for (int k = 0; k < 4; ++k)
                q[k] = *reinterpret_cast<const f32x4*>(xn + k * 256);
        }

        bf16x8 a0, a1;
        #pragma unroll
        for (int i = 0; i < 4; ++i) {
            a0[i]     = (__bf16)r0[i];
            a0[4 + i] = (__bf16)r1[i];
            a1[i]     = (__bf16)r2[i];
            a1[4 + i] = (__bf16)r3[i];
        }

        f32x4 acc[4];
        #pragma unroll
        for (int nt = 0; nt < 4; ++nt) {
            acc[nt] = (f32x4){0.f, 0.f, 0.f, 0.f};
            acc[nt] = __builtin_amdgcn_mfma_f32_16x16x32_bf16(a0, bf[0][nt], acc[nt], 0, 0, 0);
            acc[nt] = __builtin_amdgcn_mfma_f32_16x16x32_bf16(a1, bf[1][nt], acc[nt], 0, 0, 0);
        }

        // trig: position s uniform over the chunk; freqs per lane
        const int s = c & (S_ - 1);
        float cs[4], sn2[4];
        #pragma unroll
        for (int nt = 0; nt < 4; ++nt) {
            float rev = (float)s * invf[nt] * INV2PI;
            rev -= floorf(rev);
            const float sv = __builtin_amdgcn_sinf(rev);
            cs[nt]  = __builtin_amdgcn_cosf(rev);
            sn2[nt] = even ? -sv : sv;
        }

        // epilogue: res = own*cos +/- partner*sin; pi makes nt-results the
        // 4 consecutive floats at out col (even?0:32)+4u
        float* outc = out + (size_t)c * 1024;
        #pragma unroll
        for (int j = 0; j < 4; ++j) {
            f32x4 res;
            #pragma unroll
            for (int nt = 0; nt < 4; ++nt) {
                const float own = acc[nt][j];
                const float oth = __shfl_xor(own, 1, 64);
                res[nt] = fmaf(oth, sn2[nt], own * cs[nt]);
            }
            const int row  = lhi * 4 + j;
            const int col0 = (even ? 0 : 32) + 4 * u;
            *reinterpret_cast<f32x4*>(outc + row * 64 + col0) = res;
        }

        c += NWAVE;
    }
}

// ---------------------------------------------------------------------------
extern "C" void kernel_launch(void* const* d_in, const int* in_sizes, int n_in,
                              void* d_out, int out_size, void* d_ws, size_t ws_size,
                              hipStream_t stream)
{
    const float* x           = (const float*)d_in[0];
    const float* thetas      = (const float*)d_in[1];
    const float* rot_pairs   = (const float*)d_in[2];
    const float* theta_scale = (const float*)d_in[3];
    const float* rot_matrix  = (const float*)d_in[4];
    const float* inv_freq    = (const float*)d_in[5];
    float*       outp        = (float*)d_out;
    ushort_t*    Mfrag       = (ushort_t*)d_ws;       // 8 KB

    build_M_kernel<<<1, 256, 0, stream>>>(thetas, rot_pairs, theta_scale,
                                          rot_matrix, Mfrag);

    rope_mfma_kernel<<<NBLK, 256, 0, stream>>>(x, Mfrag, inv_freq, outp);
}

// Round 5
// 66.325 us; speedup vs baseline: 1.0378x; 1.0378x over previous
//
#include <hip/hip_runtime.h>

#define S_      4096
#define HD      64
#define NROT    32
#define NCHUNK  32768                 // 16-vector chunks (one per (b,s) row)
#define NBLK    2048
#define WPB     4                     // waves per block
#define NWAVE   (NBLK * WPB)          // 8192
#define NITER   (NCHUNK / NWAVE)      // 4 chunks per wave (must be even)

typedef __bf16 bf16x8 __attribute__((ext_vector_type(8)));
typedef float  f32x4  __attribute__((ext_vector_type(4)));
typedef unsigned short ushort_t;

// LDS address swizzle (involution, 16B-granular): conflict-free for both the
// linear writes and the transposed fragment reads (4 lanes per 4-bank group).
__device__ __forceinline__ int swz(int a) { return a ^ (((a >> 8) & 7) << 4); }

// ---------------------------------------------------------------------------
// Setup: M = R(Givens scan) @ rotation_matrix, bf16, MFMA-B-fragment order
// with baked column permutation pi so the epilogue's stores coalesce:
//   fragment (kt,nt): lane l, elem i  <-  M[d][e]
//     d = kt*32 + 8*(l>>4) + i                  (K dim)
//     n = l&15;  e = 8*(n>>1) + 2*nt + (n&1)    (permuted N dim)
// ---------------------------------------------------------------------------
__global__ __launch_bounds__(256) void build_M_kernel(
    const float* __restrict__ thetas,
    const float* __restrict__ rot_pairs,
    const float* __restrict__ theta_scale,
    const float* __restrict__ rot_matrix,
    ushort_t* __restrict__ Mfrag)            // 4096 ushorts (8 KB)
{
    __shared__ float R[HD][HD + 1];
    __shared__ float RM[HD][HD];
    __shared__ float Msh[HD][HD];
    const int t = threadIdx.x;

    for (int k = t; k < HD * HD; k += 256) {
        int r = k >> 6, c = k & 63;
        R[r][c]  = (r == c) ? 1.0f : 0.0f;
        RM[r][c] = rot_matrix[k];
    }
    __syncthreads();

    if (t < HD) {
        const float ts = theta_scale[0];
        #pragma unroll 1
        for (int k = 0; k < NROT; ++k) {
            const int   i  = (int)rot_pairs[2 * k];
            const int   j  = (int)rot_pairs[2 * k + 1];
            const float th = thetas[k] * ts;
            const float sn = sinf(th);
            const float cs = cosf(th);
            const float ri = R[t][i];
            const float rj = R[t][j];
            if (i == j) {
                R[t][i] = ri * cs;   // reference's .at chain leaves G[i,i]=c
            } else {
                R[t][i] = fmaf(ri, cs,  rj * sn);
                R[t][j] = fmaf(rj, cs, -ri * sn);
            }
        }
    }
    __syncthreads();

    {
        const int e  = t & 63;
        const int dg = t >> 6;
        for (int d = dg * 16; d < dg * 16 + 16; ++d) {
            float acc = 0.0f;
            #pragma unroll
            for (int k = 0; k < HD; ++k) acc = fmaf(R[d][k], RM[k][e], acc);
            Msh[d][e] = acc;
        }
    }
    __syncthreads();

    for (int k = t; k < 8 * 512; k += 256) {
        const int f  = k >> 9;          // fragment 0..7
        const int ln = (k >> 3) & 63;   // lane
        const int i  = k & 7;           // element
        const int kt = f >> 2, nt = f & 3;
        const int d  = kt * 32 + ((ln >> 4) * 8) + i;
        const int n  = ln & 15;
        const int e  = 8 * (n >> 1) + 2 * nt + (n & 1);   // pi permutation
        union { __bf16 h; ushort_t u; } cvt;
        cvt.h = (__bf16)Msh[d][e];
        Mfrag[k] = cvt.u;
    }
}

// ---------------------------------------------------------------------------
// One chunk's work: stage q -> LDS (swizzled), fragment reads, optionally
// issue the next-next chunk's loads into the freed q registers, 8 MFMAs,
// RoPE epilogue, 4 coalesced NON-TEMPORAL dwordx4 stores.
// ---------------------------------------------------------------------------
__device__ __forceinline__ void process_chunk(
    f32x4 (&q)[4], int c, bool pref, const float* __restrict__ prefp,
    char* wbuf, const int (&wr_off)[4], const int (&rd_off)[4],
    const bf16x8 (&bf)[2][4], const f32x4& invf,
    bool even, int lhi, int u, float* __restrict__ out)
{
    const float INV2PI = 0.15915494309189535f;

    // stage current chunk to LDS (swizzled)
    #pragma unroll
    for (int k = 0; k < 4; ++k)
        *reinterpret_cast<f32x4*>(wbuf + wr_off[k]) = q[k];

    // transposed fragment reads (conflict-free)
    const f32x4 r0 = *reinterpret_cast<const f32x4*>(wbuf + rd_off[0]);
    const f32x4 r1 = *reinterpret_cast<const f32x4*>(wbuf + rd_off[1]);
    const f32x4 r2 = *reinterpret_cast<const f32x4*>(wbuf + rd_off[2]);
    const f32x4 r3 = *reinterpret_cast<const f32x4*>(wbuf + rd_off[3]);

    // q registers are free now: issue loads for chunk c + 2*NWAVE
    if (pref) {
        #pragma unroll
        for (int k = 0; k < 4; ++k)
            q[k] = *reinterpret_cast<const f32x4*>(prefp + k * 256);
    }

    bf16x8 a0, a1;
    #pragma unroll
    for (int i = 0; i < 4; ++i) {
        a0[i]     = (__bf16)r0[i];
        a0[4 + i] = (__bf16)r1[i];
        a1[i]     = (__bf16)r2[i];
        a1[4 + i] = (__bf16)r3[i];
    }

    f32x4 acc[4];
    #pragma unroll
    for (int nt = 0; nt < 4; ++nt) {
        acc[nt] = (f32x4){0.f, 0.f, 0.f, 0.f};
        acc[nt] = __builtin_amdgcn_mfma_f32_16x16x32_bf16(a0, bf[0][nt], acc[nt], 0, 0, 0);
        acc[nt] = __builtin_amdgcn_mfma_f32_16x16x32_bf16(a1, bf[1][nt], acc[nt], 0, 0, 0);
    }

    // trig: position s uniform over the chunk; freqs per lane
    const int s = c & (S_ - 1);
    float cs[4], sn2[4];
    #pragma unroll
    for (int nt = 0; nt < 4; ++nt) {
        float rev = (float)s * invf[nt] * INV2PI;
        rev -= floorf(rev);
        const float sv = __builtin_amdgcn_sinf(rev);
        cs[nt]  = __builtin_amdgcn_cosf(rev);
        sn2[nt] = even ? -sv : sv;
    }

    // epilogue: res = own*cos +/- partner*sin; pi makes the 4 nt-results
    // contiguous at out col (even?0:32)+4u. Non-temporal: don't evict x
    // from L3 with the write stream.
    float* outc = out + (size_t)c * 1024;
    #pragma unroll
    for (int j = 0; j < 4; ++j) {
        f32x4 res;
        #pragma unroll
        for (int nt = 0; nt < 4; ++nt) {
            const float own = acc[nt][j];
            const float oth = __shfl_xor(own, 1, 64);
            res[nt] = fmaf(oth, sn2[nt], own * cs[nt]);
        }
        const int row  = lhi * 4 + j;
        const int col0 = (even ? 0 : 32) + 4 * u;
        __builtin_nontemporal_store(
            res, reinterpret_cast<f32x4*>(outc + row * 64 + col0));
    }
}

// ---------------------------------------------------------------------------
// Main: one wave per chunk-iteration, depth-2 load pipeline (two register
// sets qa/qb keep ~8 KB of loads outstanding per wave). Per-wave private
// LDS buffer, no barriers; DS ops are in-order per wave. All waitcnts left
// to the compiler (hazard-precise).
// ---------------------------------------------------------------------------
__global__ __launch_bounds__(256) void rope_mfma_kernel(
    const float* __restrict__ x,
    const ushort_t* __restrict__ Mfrag,
    const float* __restrict__ inv_freq,
    float* __restrict__ out)
{
    __shared__ __align__(16) float lbuf[WPB * 1024];   // 16 KB: 4 KB per wave
    const int t    = threadIdx.x;
    const int lane = t & 63;
    const int w    = t >> 6;
    const int l15  = lane & 15;
    const int lhi  = lane >> 4;
    const int u    = l15 >> 1;
    const bool even = (lane & 1) == 0;
    char* wbuf = reinterpret_cast<char*>(lbuf) + w * 4096;

    const int c0 = blockIdx.x * WPB + w;          // first chunk for this wave

    // issue both pipeline stages' loads first (coalesced: lane*16 B)
    f32x4 qa[4], qb[4];
    {
        const float* xa = x + (size_t)c0 * 1024 + lane * 4;
        const float* xb = xa + (size_t)NWAVE * 1024;
        #pragma unroll
        for (int k = 0; k < 4; ++k) qa[k] = *reinterpret_cast<const f32x4*>(xa + k * 256);
        #pragma unroll
        for (int k = 0; k < 4; ++k) qb[k] = *reinterpret_cast<const f32x4*>(xb + k * 256);
    }

    // B fragments (32 VGPRs)
    bf16x8 bf[2][4];
    #pragma unroll
    for (int kt = 0; kt < 2; ++kt)
        #pragma unroll
        for (int nt = 0; nt < 4; ++nt)
            bf[kt][nt] = *reinterpret_cast<const bf16x8*>(
                Mfrag + ((kt * 4 + nt) * 512 + lane * 8));

    // 4 contiguous freqs per lane: out cols 4u..4u+3 (mod 32)
    const f32x4 invf = *reinterpret_cast<const f32x4*>(inv_freq + 4 * u);

    // precomputed swizzled LDS byte offsets
    int wr_off[4], rd_off[4];
    #pragma unroll
    for (int k = 0; k < 4; ++k) {
        wr_off[k] = swz(k * 1024 + lane * 16);
        rd_off[k] = swz(l15 * 256 + lhi * 32 + (k & 1) * 16 + (k >> 1) * 128);
    }

    int c = c0;
    #pragma unroll 1
    for (int p = 0; p < NITER / 2; ++p) {
        const bool pref = (p + 1 < NITER / 2);
        const float* pa = x + (size_t)(c + 2 * NWAVE) * 1024 + lane * 4;
        const float* pb = pa + (size_t)NWAVE * 1024;
        process_chunk(qa, c,         pref, pa, wbuf, wr_off, rd_off,
                      bf, invf, even, lhi, u, out);
        process_chunk(qb, c + NWAVE, pref, pb, wbuf, wr_off, rd_off,
                      bf, invf, even, lhi, u, out);
        c += 2 * NWAVE;
    }
}

// ---------------------------------------------------------------------------
extern "C" void kernel_launch(void* const* d_in, const int* in_sizes, int n_in,
                              void* d_out, int out_size, void* d_ws, size_t ws_size,
                              hipStream_t stream)
{
    const float* x           = (const float*)d_in[0];
    const float* thetas      = (const float*)d_in[1];
    const float* rot_pairs   = (const float*)d_in[2];
    const float* theta_scale = (const float*)d_in[3];
    const float* rot_matrix  = (const float*)d_in[4];
    const float* inv_freq    = (const float*)d_in[5];
    float*       outp        = (float*)d_out;
    ushort_t*    Mfrag       = (ushort_t*)d_ws;       // 8 KB

    build_M_kernel<<<1, 256, 0, stream>>>(thetas, rot_pairs, theta_scale,
                                          rot_matrix, Mfrag);

    rope_mfma_kernel<<<NBLK, 256, 0, stream>>>(x, Mfrag, inv_freq, outp);
}

// Round 6
// 51.957 us; speedup vs baseline: 1.3248x; 1.2765x over previous
//
#include <hip/hip_runtime.h>

#define S_      4096
#define NROT    32
#define NCHUNK  32768                 // 16-vector chunks (one per (b,s) row)
#define NBLK    2048
#define WPB     4                     // waves per block
#define NWAVE   (NBLK * WPB)          // 8192
#define NITER   (NCHUNK / NWAVE)      // 4 chunks per wave (even)
#define MST     68                    // padded LDS stride for M (floats): keeps
                                      // 16B alignment (68%4==0) + bank spread

typedef __bf16 bf16x8 __attribute__((ext_vector_type(8)));
typedef float  f32x4  __attribute__((ext_vector_type(4)));

// LDS address swizzle (involution, 16B-granular): conflict-free for both the
// linear writes and the transposed fragment reads.
__device__ __forceinline__ int swz(int a) { return a ^ (((a >> 8) & 7) << 4); }

// Prologue M-scratch and main-loop chunk buffers share one LDS allocation
// (phases separated by barriers).
union Scratch {
    float M[64][MST];                 // 17408 B (prologue)
    float chunk[WPB][1024];           // 16384 B (main loop, 4 KB per wave)
};

// ---------------------------------------------------------------------------
// Fused kernel. Prologue (per block, redundant, ~2 us, overlapped with the
// first chunk's global loads):
//   M = G_1 * (G_2 * (... (G_32 * rotation_matrix)))   [left-apply, row ops]
//   row_i' = c*row_i - s*row_j ; row_j' = s*row_i + c*row_j  (i==j: c*row_i)
// then gather bf16 B-fragments (pi-permuted so epilogue stores coalesce):
//   frag (kt,nt): lane l, elem i <- M[d][e],
//     d = kt*32 + 8*(l>>4) + i;  n = l&15;  e = 8*(n>>1) + 2*nt + (n&1)
// Main loop (per wave, private 4 KB LDS buffer, no barriers): depth-2
// reg-staged stream, swizzled LDS transpose, 8 MFMAs, RoPE epilogue via
// shfl_xor(1), 4 coalesced non-temporal dwordx4 stores per chunk.
// ---------------------------------------------------------------------------
__global__ __launch_bounds__(256) void rope_fused_kernel(
    const float* __restrict__ x,
    const float* __restrict__ thetas,
    const float* __restrict__ rot_pairs,
    const float* __restrict__ theta_scale,
    const float* __restrict__ rot_matrix,
    const float* __restrict__ inv_freq,
    float* __restrict__ out)
{
    __shared__ __align__(16) Scratch sc;
    __shared__ float trig[NROT][2];

    const int t    = threadIdx.x;
    const int lane = t & 63;
    const int w    = t >> 6;
    const int l15  = lane & 15;
    const int lhi  = lane >> 4;
    const int u    = l15 >> 1;
    const bool even = (lane & 1) == 0;

    const int c0 = blockIdx.x * WPB + w;          // first chunk for this wave

    // ---- issue first chunk's loads immediately (latency hides under prologue)
    f32x4 qa[4], qb[4];
    {
        const float* xa = x + (size_t)c0 * 1024 + lane * 4;
        #pragma unroll
        for (int k = 0; k < 4; ++k)
            qa[k] = *reinterpret_cast<const f32x4*>(xa + k * 256);
    }

    // ---- stage rotation_matrix into padded LDS M (coalesced, aligned)
    {
        const int row = t >> 2, c4 = (t & 3) * 16;
        const float* src = rot_matrix + row * 64 + c4;
        #pragma unroll
        for (int j = 0; j < 4; ++j)
            *reinterpret_cast<f32x4*>(&sc.M[row][c4 + 4 * j]) =
                *reinterpret_cast<const f32x4*>(src + 4 * j);
    }
    // trig precompute (wave 0; ordered before the scan by program order)
    if (t < NROT) {
        const float th = thetas[t] * theta_scale[0];
        trig[t][0] = cosf(th);
        trig[t][1] = sinf(th);
    }
    __syncthreads();

    // ---- Givens scan, left-applied in reverse input order (wave 0 only;
    //      lane t owns column t; banks (4*row + t) % 32 -> conflict-free)
    if (t < 64) {
        #pragma unroll
        for (int k = NROT - 1; k >= 0; --k) {
            const int   i = (int)rot_pairs[2 * k];
            const int   j = (int)rot_pairs[2 * k + 1];
            const float c = trig[k][0];
            const float s = trig[k][1];
            const float mi = sc.M[i][t];
            const float mj = sc.M[j][t];
            if (i == j) {
                sc.M[i][t] = c * mi;   // reference's .at chain leaves G[i,i]=c
            } else {
                sc.M[i][t] = fmaf(c, mi, -s * mj);
                sc.M[j][t] = fmaf(s, mi,  c * mj);
            }
        }
    }
    __syncthreads();

    // ---- gather pi-permuted bf16 B-fragments straight from LDS M (one-time)
    bf16x8 bf[2][4];
    {
        const int n = l15;
        #pragma unroll
        for (int kt = 0; kt < 2; ++kt)
            #pragma unroll
            for (int nt = 0; nt < 4; ++nt) {
                const int e = 8 * (n >> 1) + 2 * nt + (n & 1);
                bf16x8 v;
                #pragma unroll
                for (int i2 = 0; i2 < 8; ++i2)
                    v[i2] = (__bf16)sc.M[kt * 32 + 8 * lhi + i2][e];
                bf[kt][nt] = v;
            }
    }
    __syncthreads();   // M scratch dead; chunk buffers may now be written

    // ---- main-loop constants
    const f32x4 invf = *reinterpret_cast<const f32x4*>(inv_freq + 4 * u);
    const float INV2PI = 0.15915494309189535f;
    char* wbuf = reinterpret_cast<char*>(sc.chunk[w]);

    int wr_off[4], rd_off[4];
    #pragma unroll
    for (int k = 0; k < 4; ++k) {
        wr_off[k] = swz(k * 1024 + lane * 16);
        rd_off[k] = swz(l15 * 256 + lhi * 32 + (k & 1) * 16 + (k >> 1) * 128);
    }

    // second pipeline stage's loads
    {
        const float* xb = x + (size_t)(c0 + NWAVE) * 1024 + lane * 4;
        #pragma unroll
        for (int k = 0; k < 4; ++k)
            qb[k] = *reinterpret_cast<const f32x4*>(xb + k * 256);
    }

    // ---- streaming main loop (depth-2: qa/qb)
    int c = c0;
    #pragma unroll 1
    for (int p = 0; p < NITER / 2; ++p) {
        const bool pref = (p + 1 < NITER / 2);
        #pragma unroll
        for (int half = 0; half < 2; ++half) {
            f32x4* q = half ? qb : qa;
            const int cc = c + half * NWAVE;

            // stage current chunk to LDS (swizzled)
            #pragma unroll
            for (int k = 0; k < 4; ++k)
                *reinterpret_cast<f32x4*>(wbuf + wr_off[k]) = q[k];

            // q registers dead: issue loads for chunk cc + 2*NWAVE now
            if (pref) {
                const float* xn = x + (size_t)(cc + 2 * NWAVE) * 1024 + lane * 4;
                #pragma unroll
                for (int k = 0; k < 4; ++k)
                    q[k] = *reinterpret_cast<const f32x4*>(xn + k * 256);
            }

            // transposed fragment reads (conflict-free)
            const f32x4 r0 = *reinterpret_cast<const f32x4*>(wbuf + rd_off[0]);
            const f32x4 r1 = *reinterpret_cast<const f32x4*>(wbuf + rd_off[1]);
            const f32x4 r2 = *reinterpret_cast<const f32x4*>(wbuf + rd_off[2]);
            const f32x4 r3 = *reinterpret_cast<const f32x4*>(wbuf + rd_off[3]);

            bf16x8 a0, a1;
            #pragma unroll
            for (int i = 0; i < 4; ++i) {
                a0[i]     = (__bf16)r0[i];
                a0[4 + i] = (__bf16)r1[i];
                a1[i]     = (__bf16)r2[i];
                a1[4 + i] = (__bf16)r3[i];
            }

            f32x4 acc[4];
            #pragma unroll
            for (int nt = 0; nt < 4; ++nt) {
                acc[nt] = (f32x4){0.f, 0.f, 0.f, 0.f};
                acc[nt] = __builtin_amdgcn_mfma_f32_16x16x32_bf16(a0, bf[0][nt], acc[nt], 0, 0, 0);
                acc[nt] = __builtin_amdgcn_mfma_f32_16x16x32_bf16(a1, bf[1][nt], acc[nt], 0, 0, 0);
            }

            // trig: position s uniform over the chunk (chunk = b*4096 + s)
            const int s = cc & (S_ - 1);
            float cs[4], sn2[4];
            #pragma unroll
            for (int nt = 0; nt < 4; ++nt) {
                float rev = (float)s * invf[nt] * INV2PI;
                rev -= floorf(rev);
                const float sv = __builtin_amdgcn_sinf(rev);
                cs[nt]  = __builtin_amdgcn_cosf(rev);
                sn2[nt] = even ? -sv : sv;
            }

            // epilogue: pi makes the 4 nt-results contiguous -> coalesced
            // non-temporal dwordx4 stores
            float* outc = out + (size_t)cc * 1024;
            #pragma unroll
            for (int j = 0; j < 4; ++j) {
                f32x4 res;
                #pragma unroll
                for (int nt = 0; nt < 4; ++nt) {
                    const float own = acc[nt][j];
                    const float oth = __shfl_xor(own, 1, 64);
                    res[nt] = fmaf(oth, sn2[nt], own * cs[nt]);
                }
                const int row  = lhi * 4 + j;
                const int col0 = (even ? 0 : 32) + 4 * u;
                __builtin_nontemporal_store(
                    res, reinterpret_cast<f32x4*>(outc + row * 64 + col0));
            }
        }
        c += 2 * NWAVE;
    }
}

// ---------------------------------------------------------------------------
extern "C" void kernel_launch(void* const* d_in, const int* in_sizes, int n_in,
                              void* d_out, int out_size, void* d_ws, size_t ws_size,
                              hipStream_t stream)
{
    const float* x           = (const float*)d_in[0];
    const float* thetas      = (const float*)d_in[1];
    const float* rot_pairs   = (const float*)d_in[2];
    const float* theta_scale = (const float*)d_in[3];
    const float* rot_matrix  = (const float*)d_in[4];
    const float* inv_freq    = (const float*)d_in[5];
    float*       outp        = (float*)d_out;

    rope_fused_kernel<<<NBLK, 256, 0, stream>>>(
        x, thetas, rot_pairs, theta_scale, rot_matrix, inv_freq, outp);
}

// Round 7
// 50.259 us; speedup vs baseline: 1.3696x; 1.0338x over previous
//
#include <hip/hip_runtime.h>

#define S_      4096
#define NROT    32
#define NCHUNK  32768                 // 16-vector chunks (one per (b,s) row)
#define NBLK    2048
#define WPB     4                     // waves per block
#define NWAVE   (NBLK * WPB)          // 8192
#define NITER   (NCHUNK / NWAVE)      // 4 chunks per wave (even)

typedef __bf16 bf16x4 __attribute__((ext_vector_type(4)));
typedef __bf16 bf16x8 __attribute__((ext_vector_type(8)));
typedef float  f32x4  __attribute__((ext_vector_type(4)));
typedef unsigned short ushort_t;

// bf16-chunk LDS swizzle (involution on 16B granules, keyed by row bits):
// write a=(4k+lhi)*128+l15*8 and read a=l15*128+lhi*16+kt*64 both land
// 8 lanes per 4-bank group (the b64/b128 optimum) after XOR.
__device__ __forceinline__ int swzb(int a) { return a ^ (((a >> 7) & 7) << 4); }

// Prologue M matrix, fragment buffer, and main-loop chunk buffers share one
// LDS allocation (phases separated by barriers; frag aliases M rows 0..31).
union Scratch {
    float    M[64][64];               // 16 KB (prologue scan; col t owned by lane t)
    ushort_t frag[4096];              // 8 KB: 8 bf16 B-fragments x 512
    float    chunk[WPB][512];         // 8 KB: 2 KB bf16 staging per wave
};

// ---------------------------------------------------------------------------
// Fused kernel.
// Prologue: stage rotation_matrix -> M; wave0 left-applies the 32 Givens
// rotations (row-pair ops, lane t owns column t, conflict-free: bank=t%32);
// then a two-pass relayout rewrites M as pi-permuted bf16 MFMA B-fragments
// (vectorized, conflict-free) and each thread loads its 8 fragments with
// linear ds_read_b128.
//   fragment (kt,nt): lane l, elem i <- M[d][e],
//     d = kt*32 + 8*(l>>4) + i;  n = l&15;  e = 8*(n>>1) + 2*nt + (n&1)
// Main loop (per wave, private 2 KB LDS buffer, no barriers): depth-2
// reg-staged stream; f32->bf16 convert BEFORE staging (4 ds_write_b64 +
// 2 ds_read_b128 per chunk, swizzled conflict-free); 8 MFMAs; RoPE epilogue
// via shfl_xor(1); 4 coalesced non-temporal dwordx4 stores per chunk.
// ---------------------------------------------------------------------------
__global__ __launch_bounds__(256) void rope_fused_kernel(
    const float* __restrict__ x,
    const float* __restrict__ thetas,
    const float* __restrict__ rot_pairs,
    const float* __restrict__ theta_scale,
    const float* __restrict__ rot_matrix,
    const float* __restrict__ inv_freq,
    float* __restrict__ out)
{
    __shared__ __align__(16) Scratch sc;
    __shared__ float trig[NROT][2];

    const int t    = threadIdx.x;
    const int lane = t & 63;
    const int w    = t >> 6;
    const int l15  = lane & 15;
    const int lhi  = lane >> 4;
    const int u    = l15 >> 1;
    const bool even = (lane & 1) == 0;

    const int c0 = blockIdx.x * WPB + w;          // first chunk for this wave

    // ---- issue first chunk's loads immediately (hide under prologue)
    f32x4 qa[4], qb[4];
    {
        const float* xa = x + (size_t)c0 * 1024 + lane * 4;
        #pragma unroll
        for (int k = 0; k < 4; ++k)
            qa[k] = *reinterpret_cast<const f32x4*>(xa + k * 256);
    }

    // ---- stage rotation_matrix into LDS M (coalesced b128s)
    {
        const int row = t >> 2, c4 = (t & 3) * 16;
        const float* src = rot_matrix + row * 64 + c4;
        #pragma unroll
        for (int j = 0; j < 4; ++j)
            *reinterpret_cast<f32x4*>(&sc.M[row][c4 + 4 * j]) =
                *reinterpret_cast<const f32x4*>(src + 4 * j);
    }
    if (t < NROT) {
        const float th = thetas[t] * theta_scale[0];
        trig[t][0] = cosf(th);
        trig[t][1] = sinf(th);
    }
    __syncthreads();

    // ---- Givens scan, left-applied in reverse order (wave 0; lane t owns
    //      column t; bank = t%32, 2 lanes/bank -> conflict-free)
    if (t < 64) {
        #pragma unroll
        for (int k = NROT - 1; k >= 0; --k) {
            const int   i = (int)rot_pairs[2 * k];
            const int   j = (int)rot_pairs[2 * k + 1];
            const float c = trig[k][0];
            const float s = trig[k][1];
            const float mi = sc.M[i][t];
            const float mj = sc.M[j][t];
            if (i == j) {
                sc.M[i][t] = c * mi;   // reference's .at chain leaves G[i,i]=c
            } else {
                sc.M[i][t] = fmaf(c, mi, -s * mj);
                sc.M[j][t] = fmaf(s, mi,  c * mj);
            }
        }
    }
    __syncthreads();

    // ---- relayout phase A: each thread reads the 16 M values that form
    //      frag entries F = t*16 .. t*16+15 (pi-permuted gather, one-time)
    float vals[16];
    #pragma unroll
    for (int m = 0; m < 16; ++m) {
        const int F  = t * 16 + m;
        const int f  = F >> 9;
        const int ln = (F >> 3) & 63;
        const int i  = F & 7;
        const int kt = f >> 2, nt = f & 3;
        const int d  = kt * 32 + 8 * (ln >> 4) + i;
        const int n  = ln & 15;
        const int e  = 8 * (n >> 1) + 2 * nt + (n & 1);
        vals[m] = sc.M[d][e];
    }
    __syncthreads();

    // ---- relayout phase B: pack to bf16 and write 32 B linear (2x b128)
    {
        uint32_t dw[8];
        #pragma unroll
        for (int m = 0; m < 8; ++m) {
            union { __bf16 h; ushort_t s; } lo, hi;
            lo.h = (__bf16)vals[2 * m];
            hi.h = (__bf16)vals[2 * m + 1];
            dw[m] = (uint32_t)lo.s | ((uint32_t)hi.s << 16);
        }
        uint32_t* dst = reinterpret_cast<uint32_t*>(sc.frag + t * 16);
        *reinterpret_cast<uint4*>(dst)     = make_uint4(dw[0], dw[1], dw[2], dw[3]);
        *reinterpret_cast<uint4*>(dst + 4) = make_uint4(dw[4], dw[5], dw[6], dw[7]);
    }
    __syncthreads();

    // ---- every thread loads its 8 B-fragments (linear, conflict-free)
    bf16x8 bf[2][4];
    #pragma unroll
    for (int kt = 0; kt < 2; ++kt)
        #pragma unroll
        for (int nt = 0; nt < 4; ++nt)
            bf[kt][nt] = *reinterpret_cast<const bf16x8*>(
                sc.frag + ((kt * 4 + nt) * 512 + lane * 8));
    __syncthreads();   // frag region dead; chunk buffers may now be written

    // ---- second pipeline stage's loads
    {
        const float* xb = x + (size_t)(c0 + NWAVE) * 1024 + lane * 4;
        #pragma unroll
        for (int k = 0; k < 4; ++k)
            qb[k] = *reinterpret_cast<const f32x4*>(xb + k * 256);
    }

    // ---- main-loop constants
    const f32x4 invf = *reinterpret_cast<const f32x4*>(inv_freq + 4 * u);
    const float INV2PI = 0.15915494309189535f;
    char* wbuf = reinterpret_cast<char*>(sc.chunk[w]);

    int wr_off[4];
    #pragma unroll
    for (int k = 0; k < 4; ++k)
        wr_off[k] = swzb((k * 4 + lhi) * 128 + l15 * 8);
    const int rd0 = swzb(l15 * 128 + lhi * 16);
    const int rd1 = swzb(l15 * 128 + lhi * 16 + 64);

    // ---- streaming main loop (depth-2: qa/qb; per-wave LDS, no barriers)
    int c = c0;
    #pragma unroll 1
    for (int p = 0; p < NITER / 2; ++p) {
        const bool pref = (p + 1 < NITER / 2);
        #pragma unroll
        for (int half = 0; half < 2; ++half) {
            f32x4* q = half ? qb : qa;
            const int cc = c + half * NWAVE;

            // convert f32->bf16 and stage (4x ds_write_b64, swizzled)
            #pragma unroll
            for (int k = 0; k < 4; ++k) {
                bf16x4 h;
                #pragma unroll
                for (int i = 0; i < 4; ++i) h[i] = (__bf16)q[k][i];
                *reinterpret_cast<bf16x4*>(wbuf + wr_off[k]) = h;
            }

            // q registers dead: issue loads for chunk cc + 2*NWAVE now
            if (pref) {
                const float* xn = x + (size_t)(cc + 2 * NWAVE) * 1024 + lane * 4;
                #pragma unroll
                for (int k = 0; k < 4; ++k)
                    q[k] = *reinterpret_cast<const f32x4*>(xn + k * 256);
            }

            // A fragments directly from LDS (2x ds_read_b128, conflict-free)
            const bf16x8 a0 = *reinterpret_cast<const bf16x8*>(wbuf + rd0);
            const bf16x8 a1 = *reinterpret_cast<const bf16x8*>(wbuf + rd1);

            f32x4 acc[4];
            #pragma unroll
            for (int nt = 0; nt < 4; ++nt) {
                acc[nt] = (f32x4){0.f, 0.f, 0.f, 0.f};
                acc[nt] = __builtin_amdgcn_mfma_f32_16x16x32_bf16(a0, bf[0][nt], acc[nt], 0, 0, 0);
                acc[nt] = __builtin_amdgcn_mfma_f32_16x16x32_bf16(a1, bf[1][nt], acc[nt], 0, 0, 0);
            }

            // trig: position s uniform over the chunk (chunk = b*4096 + s)
            const int s = cc & (S_ - 1);
            float cs[4], sn2[4];
            #pragma unroll
            for (int nt = 0; nt < 4; ++nt) {
                float rev = (float)s * invf[nt] * INV2PI;
                rev -= floorf(rev);
                const float sv = __builtin_amdgcn_sinf(rev);
                cs[nt]  = __builtin_amdgcn_cosf(rev);
                sn2[nt] = even ? -sv : sv;
            }

            // epilogue: pi makes the 4 nt-results contiguous -> coalesced
            // non-temporal dwordx4 stores
            float* outc = out + (size_t)cc * 1024;
            #pragma unroll
            for (int j = 0; j < 4; ++j) {
                f32x4 res;
                #pragma unroll
                for (int nt = 0; nt < 4; ++nt) {
                    const float own = acc[nt][j];
                    const float oth = __shfl_xor(own, 1, 64);
                    res[nt] = fmaf(oth, sn2[nt], own * cs[nt]);
                }
                const int row  = lhi * 4 + j;
                const int col0 = (even ? 0 : 32) + 4 * u;
                __builtin_nontemporal_store(
                    res, reinterpret_cast<f32x4*>(outc + row * 64 + col0));
            }
        }
        c += 2 * NWAVE;
    }
}

// ---------------------------------------------------------------------------
extern "C" void kernel_launch(void* const* d_in, const int* in_sizes, int n_in,
                              void* d_out, int out_size, void* d_ws, size_t ws_size,
                              hipStream_t stream)
{
    const float* x           = (const float*)d_in[0];
    const float* thetas      = (const float*)d_in[1];
    const float* rot_pairs   = (const float*)d_in[2];
    const float* theta_scale = (const float*)d_in[3];
    const float* rot_matrix  = (const float*)d_in[4];
    const float* inv_freq    = (const float*)d_in[5];
    float*       outp        = (float*)d_out;

    rope_fused_kernel<<<NBLK, 256, 0, stream>>>(
        x, thetas, rot_pairs, theta_scale, rot_matrix, inv_freq, outp);
}